// Round 2
// baseline (1747.066 us; speedup 1.0000x reference)
//
#include <hip/hip_runtime.h>
#include <hip/hip_bf16.h>
#include <math.h>

// ---------- helpers ----------
__device__ inline float bf2f(unsigned short h) { return __uint_as_float(((unsigned)h) << 16); }
__device__ inline unsigned short f2bf(float f) {
    unsigned u = __float_as_uint(f);
    unsigned r = (u + 0x7FFFu + ((u >> 16) & 1u)) >> 16;
    return (unsigned short)r;
}
__device__ inline float wred(float v) {
    v += __shfl_xor(v, 1, 64);
    v += __shfl_xor(v, 2, 64);
    v += __shfl_xor(v, 4, 64);
    v += __shfl_xor(v, 8, 64);
    v += __shfl_xor(v, 16, 64);
    v += __shfl_xor(v, 32, 64);
    return v;
}
// monotone float<->uint encoding for signed atomic max
__device__ inline unsigned fenc(float f) {
    unsigned u = __float_as_uint(f);
    return (u & 0x80000000u) ? ~u : (u | 0x80000000u);
}
__device__ inline float fdec(unsigned m) {
    unsigned u = (m & 0x80000000u) ? (m ^ 0x80000000u) : ~m;
    return __uint_as_float(u);
}

#define ACLIP (1.0f - 1e-7f)

// ---------- dtype detection ----------
// f32 data read as ushort: even halfwords are low-mantissa bits -> random bf16
// exponents, ~25% have exponent >= 0xC0. Genuine bf16 hyper (|x|<1) -> 0%.
__global__ void k_detect(const unsigned short* __restrict__ hyper, int* __restrict__ flag) {
    __shared__ int total;
    int t = threadIdx.x;
    if (t == 0) total = 0;
    __syncthreads();
    int cnt = 0;
    for (int i = t * 8; i < t * 8 + 8; i++) {
        if ((i & 1) == 0) {
            unsigned e = ((unsigned)hyper[i] >> 7) & 0xFF;
            if (e >= 0xC0) cnt++;
        }
    }
    atomicAdd(&total, cnt);
    __syncthreads();
    if (t == 0) *flag = (total >= 32) ? 1 : 0;   // 1 = inputs are float32
}

// ---------- converters / fills ----------
__global__ void k_cvt(const void* __restrict__ s, float* __restrict__ d, int n,
                      const int* __restrict__ flag) {
    int i = blockIdx.x * blockDim.x + threadIdx.x;
    if (i >= n) return;
    if (*flag) d[i] = ((const float*)s)[i];
    else       d[i] = bf2f(((const unsigned short*)s)[i]);
}
__global__ void k_fill(unsigned* __restrict__ p, unsigned v, int n) {
    int i = blockIdx.x * blockDim.x + threadIdx.x;
    if (i < n) p[i] = v;
}

// ---------- stage 1: per-node prologue (wave per node) ----------
__global__ void k_node_prep(const void* __restrict__ hyper_v,
                            const void* __restrict__ dt_v,
                            const float* __restrict__ tw, const float* __restrict__ tb,
                            float* __restrict__ sf, float* __restrict__ tnode,
                            const int* __restrict__ flag, int n_dst, int n_total) {
    int wid  = (blockIdx.x * blockDim.x + threadIdx.x) >> 6;
    int lane = threadIdx.x & 63;
    if (wid >= n_total) return;
    int isf32 = *flag;
    float tval = 0.0f;
    if (wid >= n_dst) {
        int e = wid - n_dst;
        tval = isf32 ? ((const float*)dt_v)[e] : bf2f(((const unsigned short*)dt_v)[e]);
    }
    int j0 = lane * 2;
    float a0 = tval * tw[j0]     + tb[j0];
    float a1 = tval * tw[j0 + 1] + tb[j0 + 1];
    float tf0 = cosf(a0);
    float tf1 = cosf(a1);
    float h0, h1;
    if (isf32) {
        const float* hp = (const float*)hyper_v + (size_t)wid * 128 + j0;
        h0 = hp[0]; h1 = hp[1];
    } else {
        const unsigned short* hp = (const unsigned short*)hyper_v + (size_t)wid * 128 + j0;
        h0 = bf2f(hp[0]); h1 = bf2f(hp[1]);
    }
    float ptf2 = wred(tf0 * tf0 + tf1 * tf1);
    float ph2  = wred(h0 * h0 + h1 * h1);
    float pht  = wred(h0 * tf0 + h1 * tf1);
    float ntf = sqrtf(fmaxf(ptf2, 1e-30f));
    float maxn = 1.0f - 0.004f;
    float sc = (ntf > maxn) ? (maxn / ntf) : 1.0f;
    float y2 = sc * sc * ptf2, xy = sc * pht, x2 = ph2;
    float A = 1.0f + 2.0f * xy + y2;
    float B = 1.0f - x2;
    float iden = 1.0f / fmaxf(1.0f + 2.0f * xy + x2 * y2, 1e-15f);
    float s0 = (A * h0 + B * sc * tf0) * iden;
    float s1 = (A * h1 + B * sc * tf1) * iden;
    float* sp = sf + (size_t)wid * 128 + j0;
    sp[0] = s0; sp[1] = s1;
    float ps2 = wred(s0 * s0 + s1 * s1);
    float xn = sqrtf(fmaxf(ps2, 1e-30f));
    float g = atanhf(fminf(xn, ACLIP)) / xn;
    if (lane == 0) tnode[wid] = g;
}

// ---------- stage 2: GEMM  C[M,256] = A[M,128] @ W[256,128]^T  (fp32) ----------
__global__ __launch_bounds__(256) void k_gemm(const float* __restrict__ A,
                                              const float* __restrict__ W,
                                              float* __restrict__ C, int M) {
    __shared__ __align__(16) float As[64][32];    // 8 KB
    __shared__ __align__(16) float Ws[32][256];   // 32 KB
    int t = threadIdx.x;
    int row0 = blockIdx.x * 64;
    int g = t >> 6;               // row group 0..3
    int c0 = (t & 63) * 4;        // col base
    float acc[16][4];
#pragma unroll
    for (int n = 0; n < 16; n++)
#pragma unroll
        for (int j = 0; j < 4; j++) acc[n][j] = 0.0f;

    for (int k0 = 0; k0 < 128; k0 += 32) {
        __syncthreads();
        for (int q = t; q < 512; q += 256) {
            int r = q >> 3, c4 = (q & 7) * 4;
            int rr = min(row0 + r, M - 1);
            float4 v = *(const float4*)(A + (size_t)rr * 128 + k0 + c4);
            *(float4*)&As[r][c4] = v;
        }
        {
            const float* wr = W + (size_t)t * 128 + k0;
#pragma unroll
            for (int kk = 0; kk < 32; kk += 4) {
                float4 v = *(const float4*)(wr + kk);
                Ws[kk + 0][t] = v.x; Ws[kk + 1][t] = v.y;
                Ws[kk + 2][t] = v.z; Ws[kk + 3][t] = v.w;
            }
        }
        __syncthreads();
#pragma unroll
        for (int kk = 0; kk < 32; kk += 4) {
            float4 w0 = *(const float4*)&Ws[kk + 0][c0];
            float4 w1 = *(const float4*)&Ws[kk + 1][c0];
            float4 w2 = *(const float4*)&Ws[kk + 2][c0];
            float4 w3 = *(const float4*)&Ws[kk + 3][c0];
#pragma unroll
            for (int nn = 0; nn < 16; nn++) {
                float4 a4 = *(const float4*)&As[g * 16 + nn][kk];
                acc[nn][0] += a4.x * w0.x + a4.y * w1.x + a4.z * w2.x + a4.w * w3.x;
                acc[nn][1] += a4.x * w0.y + a4.y * w1.y + a4.z * w2.y + a4.w * w3.y;
                acc[nn][2] += a4.x * w0.z + a4.y * w1.z + a4.z * w2.z + a4.w * w3.z;
                acc[nn][3] += a4.x * w0.w + a4.y * w1.w + a4.z * w2.w + a4.w * w3.w;
            }
        }
    }
#pragma unroll
    for (int nn = 0; nn < 16; nn++) {
        int row = row0 + g * 16 + nn;
        if (row < M) {
            float4 v = make_float4(acc[nn][0], acc[nn][1], acc[nn][2], acc[nn][3]);
            *(float4*)(C + (size_t)row * 256 + c0) = v;
        }
    }
}

// ---------- stage 3: per-node epilogue (wave per node, in-place mx -> feat) ----------
__global__ void k_epilogue(float* __restrict__ feat, const float* __restrict__ tnode,
                           const float* __restrict__ bvec, const float* __restrict__ attn,
                           float* __restrict__ x2a, float* __restrict__ ca,
                           float* __restrict__ satt, int base, int cnt) {
    int wid  = (blockIdx.x * blockDim.x + threadIdx.x) >> 6;
    int lane = threadIdx.x & 63;
    if (wid >= cnt) return;
    int node = base + wid;
    float* row = feat + (size_t)node * 256;
    int c = lane * 4;
    float4 mx = *(float4*)(row + c);
    float4 b4 = *(const float4*)(bvec + c);
    float pm2 = wred(mx.x * mx.x + mx.y * mx.y + mx.z * mx.z + mx.w * mx.w);
    float pdb = wred(mx.x * b4.x + mx.y * b4.y + mx.z * b4.z + mx.w * b4.w);
    float pb2 = wred(b4.x * b4.x + b4.y * b4.y + b4.z * b4.z + b4.w * b4.w);
    float g = tnode[node];
    float mxn = sqrtf(fmaxf(pm2, 1e-30f));
    float sv = tanhf(mxn * g) / mxn;
    float xy = sv * pdb;
    float x2v = sv * sv * pm2;
    float y2 = pb2;
    float A = 1.0f + 2.0f * xy + y2;
    float B = 1.0f - x2v;
    float iden = 1.0f / fmaxf(1.0f + 2.0f * xy + x2v * y2, 1e-15f);
    float4 f;
    f.x = (A * sv * mx.x + B * b4.x) * iden;
    f.y = (A * sv * mx.y + B * b4.y) * iden;
    f.z = (A * sv * mx.z + B * b4.z) * iden;
    f.w = (A * sv * mx.w + B * b4.w) * iden;
    *(float4*)(row + c) = f;
    float4 at = *(const float4*)(attn + c);
    float pf2 = f.x * f.x + f.y * f.y + f.z * f.z + f.w * f.w;
    float pfa = f.x * at.x + f.y * at.y + f.z * at.z + f.w * at.w;
    float pa0 = (lane < 32) ? pfa : 0.0f;
    float pa1 = (lane < 32) ? 0.0f : pfa;
    pf2 = wred(pf2); pa0 = wred(pa0); pa1 = wred(pa1);
    float nf = sqrtf(fmaxf(pf2, 1e-30f));
    float cl = atanhf(fminf(nf, ACLIP)) / nf;
    if (lane == 0) {
        x2a[node] = pf2;
        ca[node] = cl;
        satt[(size_t)node * 2 + 0] = cl * pa0;
        satt[(size_t)node * 2 + 1] = cl * pa1;
    }
}

// ---------- stage 4: edge distance + segment max of inv (wave per edge) ----------
__global__ void k_edge_dist(const float* __restrict__ feat, const float* __restrict__ x2a,
                            const int* __restrict__ src_idx, const int* __restrict__ dst_idx,
                            float* __restrict__ invd, unsigned* __restrict__ max_inv, int n_edge) {
    int wid  = (blockIdx.x * blockDim.x + threadIdx.x) >> 6;
    int lane = threadIdx.x & 63;
    if (wid >= n_edge) return;
    int s = src_idx[wid], d = dst_idx[wid];
    int c = lane * 4;
    float4 xv = *(const float4*)(feat + (size_t)s * 256 + c);
    float4 yv = *(const float4*)(feat + (size_t)d * 256 + c);
    float pd = wred(xv.x * yv.x + xv.y * yv.y + xv.z * yv.z + xv.w * yv.w);
    float x2 = x2a[s], y2 = x2a[d];
    float A = 1.0f - 2.0f * pd + y2;
    float B = 1.0f - x2;
    float iden = 1.0f / fmaxf(1.0f - 2.0f * pd + x2 * y2, 1e-15f);
    float n0 = (B * yv.x - A * xv.x) * iden;
    float n1 = (B * yv.y - A * xv.y) * iden;
    float n2 = (B * yv.z - A * xv.z) * iden;
    float n3 = (B * yv.w - A * xv.w) * iden;
    float p2 = wred(n0 * n0 + n1 * n1 + n2 * n2 + n3 * n3);
    if (lane == 0) {
        float nrm = sqrtf(fmaxf(p2, 1e-30f));
        float dd = 2.0f * atanhf(fminf(nrm, ACLIP));
        float iv = 1.0f / (1e-15f + dd);
        invd[wid] = iv;
        atomicMax(max_inv + d, __float_as_uint(iv));  // iv>0: uint order == float order
    }
}

// ---------- stage 5: softmax chains (thread per edge) ----------
__global__ void k_edge_z(const float* __restrict__ invd, const int* __restrict__ dst_idx,
                         const unsigned* __restrict__ max_inv, float* __restrict__ zbuf,
                         float* __restrict__ sum_z, int n_edge) {
    int i = blockIdx.x * blockDim.x + threadIdx.x;
    if (i >= n_edge) return;
    int d = dst_idx[i];
    float z = expf(invd[i] - __uint_as_float(max_inv[d]));
    zbuf[i] = z;
    atomicAdd(sum_z + d, z);
}

__global__ void k_edge_e(const float* __restrict__ zbuf, const float* __restrict__ sum_z,
                         const int* __restrict__ src_idx, const int* __restrict__ dst_idx,
                         const float* __restrict__ satt, float* __restrict__ ebuf,
                         unsigned* __restrict__ max_e, int n_edge) {
    int i = blockIdx.x * blockDim.x + threadIdx.x;
    if (i >= n_edge) return;
    int s = src_idx[i], d = dst_idx[i];
    float dsm = zbuf[i] / sum_z[d];
#pragma unroll
    for (int h = 0; h < 2; h++) {
        float e = (satt[(size_t)s * 2 + h] + satt[(size_t)d * 2 + h]) * dsm;
        e = (e > 0.0f) ? e : 0.2f * e;
        ebuf[(size_t)i * 2 + h] = e;
        atomicMax(max_e + (size_t)d * 2 + h, fenc(e));
    }
}

__global__ void k_edge_z2(const float* __restrict__ ebuf, const int* __restrict__ dst_idx,
                          const unsigned* __restrict__ max_e, float* __restrict__ z2buf,
                          float* __restrict__ sum_e, int n_edge) {
    int i = blockIdx.x * blockDim.x + threadIdx.x;
    if (i >= n_edge) return;
    int d = dst_idx[i];
#pragma unroll
    for (int h = 0; h < 2; h++) {
        float z = expf(ebuf[(size_t)i * 2 + h] - fdec(max_e[(size_t)d * 2 + h]));
        z2buf[(size_t)i * 2 + h] = z;
        atomicAdd(sum_e + (size_t)d * 2 + h, z);
    }
}

// ---------- stage 6: weighted scatter (wave per edge) ----------
__global__ void k_edge_scatter(const float* __restrict__ feat, const float* __restrict__ z2buf,
                               const float* __restrict__ sum_e, const float* __restrict__ ca,
                               const int* __restrict__ src_idx, const int* __restrict__ dst_idx,
                               float* __restrict__ ft, int n_edge) {
    int wid  = (blockIdx.x * blockDim.x + threadIdx.x) >> 6;
    int lane = threadIdx.x & 63;
    if (wid >= n_edge) return;
    int s = src_idx[wid], d = dst_idx[wid];
    int h = lane >> 5;
    float a = z2buf[(size_t)wid * 2 + h] / sum_e[(size_t)d * 2 + h];
    float w = a * ca[s];
    int c = lane * 4;
    const float* xr = feat + (size_t)s * 256 + c;
    float* fr = ft + (size_t)d * 256 + c;
    atomicAdd(fr + 0, w * xr[0]);
    atomicAdd(fr + 1, w * xr[1]);
    atomicAdd(fr + 2, w * xr[2]);
    atomicAdd(fr + 3, w * xr[3]);
}

// ---------- stage 7: expmap0 + store (wave per row), dtype-branched ----------
__global__ void k_out(const float* __restrict__ ft, void* __restrict__ out,
                      const int* __restrict__ flag, int n_dst) {
    int wid  = (blockIdx.x * blockDim.x + threadIdx.x) >> 6;
    int lane = threadIdx.x & 63;
    if (wid >= n_dst) return;
    int c = lane * 4;
    float4 v = *(const float4*)(ft + (size_t)wid * 256 + c);
    float p2 = wred(v.x * v.x + v.y * v.y + v.z * v.z + v.w * v.w);
    float n = sqrtf(fmaxf(p2, 1e-30f));
    float sc = tanhf(n) / n;
    if (*flag) {
        float4 o = make_float4(v.x * sc, v.y * sc, v.z * sc, v.w * sc);
        *(float4*)((float*)out + (size_t)wid * 256 + c) = o;
    } else {
        ushort4 o;
        o.x = f2bf(v.x * sc); o.y = f2bf(v.y * sc);
        o.z = f2bf(v.z * sc); o.w = f2bf(v.w * sc);
        *(ushort4*)((unsigned short*)out + (size_t)wid * 256 + c) = o;
    }
}

// ---------- host ----------
extern "C" void kernel_launch(void* const* d_in, const int* in_sizes, int n_in,
                              void* d_out, int out_size, void* d_ws, size_t ws_size,
                              hipStream_t stream) {
    const void* hyper  = d_in[0];
    const void* dt     = d_in[1];
    const void* time_w = d_in[2];
    const void* time_b = d_in[3];
    const void* w_src  = d_in[4];
    const void* b_src  = d_in[5];
    const void* w_dst  = d_in[6];
    const void* b_dst  = d_in[7];
    const void* attn   = d_in[8];
    const int* src_idx = (const int*)d_in[9];
    const int* dst_idx = (const int*)d_in[10];

    const int DIMN = 128, HD = 256;
    int n_edge  = in_sizes[1];
    int n_total = in_sizes[0] / DIMN;
    int n_dst   = n_total - n_edge;

    float* ws = (float*)d_ws;
    size_t off = 0;
    auto alloc = [&](size_t n) { float* p = ws + off; off += n; return p; };
    float* p_tw    = alloc(DIMN);
    float* p_tb    = alloc(DIMN);
    float* p_wsrc  = alloc((size_t)HD * DIMN);
    float* p_wdst  = alloc((size_t)HD * DIMN);
    float* p_bsrc  = alloc(HD);
    float* p_bdst  = alloc(HD);
    float* p_attn  = alloc(HD);
    int*   p_flag  = (int*)alloc(4);
    float* p_sf    = alloc((size_t)n_total * DIMN);   // dead after GEMMs -> overlaid below
    float* p_mx    = alloc((size_t)n_total * HD);     // mx, then feat in-place
    float* p_tnode = alloc(n_total);
    float* p_call  = alloc(n_total);
    float* p_x2    = alloc(n_total);
    float* p_satt  = alloc((size_t)n_total * 2);
    // ---- overlay region inside p_sf (valid after GEMMs complete) ----
    size_t ooff = 0;
    auto oalloc = [&](size_t n) { float* p = p_sf + ooff; ooff += n; return p; };
    float* p_inv   = oalloc(n_edge);
    float* p_z     = oalloc(n_edge);
    float* p_e     = oalloc((size_t)n_edge * 2);
    float* p_z2    = oalloc((size_t)n_edge * 2);
    float* p_ft    = oalloc((size_t)n_dst * HD);   // contiguous zero region starts here
    float* p_sumz  = oalloc(n_dst);
    float* p_sume  = oalloc((size_t)n_dst * 2);
    float* p_maxinv= oalloc(n_dst);
    float* p_maxe  = oalloc((size_t)n_dst * 2);
    (void)ws_size;

    const int TB = 256;
    auto cdiv = [](int a, int b) { return (a + b - 1) / b; };

    // dtype detection (flag must exist before converters run)
    k_detect<<<1, TB, 0, stream>>>((const unsigned short*)hyper, p_flag);

    // param conversion -> fp32
    k_cvt<<<cdiv(DIMN, TB), TB, 0, stream>>>(time_w, p_tw, DIMN, p_flag);
    k_cvt<<<cdiv(DIMN, TB), TB, 0, stream>>>(time_b, p_tb, DIMN, p_flag);
    k_cvt<<<cdiv(HD * DIMN, TB), TB, 0, stream>>>(w_src, p_wsrc, HD * DIMN, p_flag);
    k_cvt<<<cdiv(HD * DIMN, TB), TB, 0, stream>>>(w_dst, p_wdst, HD * DIMN, p_flag);
    k_cvt<<<cdiv(HD, TB), TB, 0, stream>>>(b_src, p_bsrc, HD, p_flag);
    k_cvt<<<cdiv(HD, TB), TB, 0, stream>>>(b_dst, p_bdst, HD, p_flag);
    k_cvt<<<cdiv(HD, TB), TB, 0, stream>>>(attn, p_attn, HD, p_flag);

    // stage 1: node prologue (writes all of p_sf)
    k_node_prep<<<cdiv(n_total, 4), TB, 0, stream>>>(hyper, dt, p_tw, p_tb,
                                                     p_sf, p_tnode, p_flag, n_dst, n_total);

    // stage 2: GEMMs
    k_gemm<<<cdiv(n_dst, 64), TB, 0, stream>>>(p_sf, p_wdst, p_mx, n_dst);
    k_gemm<<<cdiv(n_edge, 64), TB, 0, stream>>>(p_sf + (size_t)n_dst * DIMN, p_wsrc,
                                                p_mx + (size_t)n_dst * HD, n_edge);

    // accumulator init — AFTER GEMMs (buffers overlay p_sf)
    int zeroN = n_dst * (HD + 1 + 2 + 1);  // ft + sum_z + sum_e + max_inv
    k_fill<<<cdiv(zeroN, TB), TB, 0, stream>>>((unsigned*)p_ft, 0u, zeroN);
    k_fill<<<cdiv(2 * n_dst, TB), TB, 0, stream>>>((unsigned*)p_maxe, 0x007FFFFFu, 2 * n_dst);

    // stage 3: epilogues
    k_epilogue<<<cdiv(n_dst, 4), TB, 0, stream>>>(p_mx, p_tnode, p_bdst, p_attn,
                                                  p_x2, p_call, p_satt, 0, n_dst);
    k_epilogue<<<cdiv(n_edge, 4), TB, 0, stream>>>(p_mx, p_tnode, p_bsrc, p_attn,
                                                   p_x2, p_call, p_satt, n_dst, n_edge);

    // stage 4-5: edge distance + two segment softmaxes
    k_edge_dist<<<cdiv(n_edge, 4), TB, 0, stream>>>(p_mx, p_x2, src_idx, dst_idx,
                                                    p_inv, (unsigned*)p_maxinv, n_edge);
    k_edge_z<<<cdiv(n_edge, TB), TB, 0, stream>>>(p_inv, dst_idx, (unsigned*)p_maxinv,
                                                  p_z, p_sumz, n_edge);
    k_edge_e<<<cdiv(n_edge, TB), TB, 0, stream>>>(p_z, p_sumz, src_idx, dst_idx, p_satt,
                                                  p_e, (unsigned*)p_maxe, n_edge);
    k_edge_z2<<<cdiv(n_edge, TB), TB, 0, stream>>>(p_e, dst_idx, (unsigned*)p_maxe,
                                                   p_z2, p_sume, n_edge);

    // stage 6: scatter-accumulate ft
    k_edge_scatter<<<cdiv(n_edge, 4), TB, 0, stream>>>(p_mx, p_z2, p_sume, p_call,
                                                       src_idx, dst_idx, p_ft, n_edge);

    // stage 7: expmap0 -> out (dtype per flag)
    k_out<<<cdiv(n_dst, 4), TB, 0, stream>>>(p_ft, d_out, p_flag, n_dst);
}

// Round 3
// 1112.278 us; speedup vs baseline: 1.5707x; 1.5707x over previous
//
#include <hip/hip_runtime.h>
#include <hip/hip_bf16.h>
#include <math.h>

// ---------- helpers ----------
__device__ inline float bf2f(unsigned short h) { return __uint_as_float(((unsigned)h) << 16); }
__device__ inline unsigned short f2bf(float f) {
    unsigned u = __float_as_uint(f);
    unsigned r = (u + 0x7FFFu + ((u >> 16) & 1u)) >> 16;
    return (unsigned short)r;
}
__device__ inline float wred(float v) {
    v += __shfl_xor(v, 1, 64);
    v += __shfl_xor(v, 2, 64);
    v += __shfl_xor(v, 4, 64);
    v += __shfl_xor(v, 8, 64);
    v += __shfl_xor(v, 16, 64);
    v += __shfl_xor(v, 32, 64);
    return v;
}
__device__ inline float wredmax(float v) {
    v = fmaxf(v, __shfl_xor(v, 1, 64));
    v = fmaxf(v, __shfl_xor(v, 2, 64));
    v = fmaxf(v, __shfl_xor(v, 4, 64));
    v = fmaxf(v, __shfl_xor(v, 8, 64));
    v = fmaxf(v, __shfl_xor(v, 16, 64));
    v = fmaxf(v, __shfl_xor(v, 32, 64));
    return v;
}
// block (256 thr = 4 waves) reductions; red = shared float[4]
__device__ inline float bsum(float v, float* red) {
    v = wred(v);
    if ((threadIdx.x & 63) == 0) red[threadIdx.x >> 6] = v;
    __syncthreads();
    float r = red[0] + red[1] + red[2] + red[3];
    __syncthreads();
    return r;
}
__device__ inline float bmax(float v, float* red) {
    v = wredmax(v);
    if ((threadIdx.x & 63) == 0) red[threadIdx.x >> 6] = v;
    __syncthreads();
    float r = fmaxf(fmaxf(red[0], red[1]), fmaxf(red[2], red[3]));
    __syncthreads();
    return r;
}

#define ACLIP (1.0f - 1e-7f)

// ---------- dtype detection ----------
__global__ void k_detect(const unsigned short* __restrict__ hyper, int* __restrict__ flag) {
    __shared__ int total;
    int t = threadIdx.x;
    if (t == 0) total = 0;
    __syncthreads();
    int cnt = 0;
    for (int i = t * 8; i < t * 8 + 8; i++) {
        if ((i & 1) == 0) {
            unsigned e = ((unsigned)hyper[i] >> 7) & 0xFF;
            if (e >= 0xC0) cnt++;
        }
    }
    atomicAdd(&total, cnt);
    __syncthreads();
    if (t == 0) *flag = (total >= 32) ? 1 : 0;   // 1 = inputs are float32
}

// ---------- converters / fills ----------
__global__ void k_cvt(const void* __restrict__ s, float* __restrict__ d, int n,
                      const int* __restrict__ flag) {
    int i = blockIdx.x * blockDim.x + threadIdx.x;
    if (i >= n) return;
    if (*flag) d[i] = ((const float*)s)[i];
    else       d[i] = bf2f(((const unsigned short*)s)[i]);
}
__global__ void k_fill(unsigned* __restrict__ p, unsigned v, int n) {
    int i = blockIdx.x * blockDim.x + threadIdx.x;
    if (i < n) p[i] = v;
}

// ---------- CSR build ----------
__global__ void k_hist(const int* __restrict__ dst_idx, int* __restrict__ deg, int n_edge) {
    int i = blockIdx.x * blockDim.x + threadIdx.x;
    if (i < n_edge) atomicAdd(deg + dst_idx[i], 1);
}
// single block, 1024 threads: exclusive scan of deg -> rowptr/cursor
__global__ __launch_bounds__(1024) void k_scan(const int* __restrict__ deg,
                                               int* __restrict__ rowptr,
                                               int* __restrict__ cursor, int n) {
    __shared__ int part[1024];
    int t = threadIdx.x;
    int chunk = (n + 1023) >> 10;
    int lo = t * chunk, hi = min(lo + chunk, n);
    int s = 0;
    for (int i = lo; i < hi; i++) s += deg[i];
    part[t] = s;
    __syncthreads();
    for (int dd = 1; dd < 1024; dd <<= 1) {
        int v = (t >= dd) ? part[t - dd] : 0;
        __syncthreads();
        part[t] += v;
        __syncthreads();
    }
    int base = (t == 0) ? 0 : part[t - 1];
    for (int i = lo; i < hi; i++) {
        rowptr[i] = base; cursor[i] = base;
        base += deg[i];
    }
    if (t == 0) rowptr[n] = part[1023];
}
__global__ void k_scatter_edges(const int* __restrict__ src_idx, const int* __restrict__ dst_idx,
                                int* __restrict__ cursor, int* __restrict__ es,
                                int* __restrict__ ed, int n_edge) {
    int i = blockIdx.x * blockDim.x + threadIdx.x;
    if (i >= n_edge) return;
    int d = dst_idx[i];
    int slot = atomicAdd(cursor + d, 1);
    es[slot] = src_idx[i];
    ed[slot] = d;
}

// ---------- stage 1: per-node prologue (wave per node) ----------
__global__ void k_node_prep(const void* __restrict__ hyper_v,
                            const void* __restrict__ dt_v,
                            const float* __restrict__ tw, const float* __restrict__ tb,
                            float* __restrict__ sf, float* __restrict__ tnode,
                            const int* __restrict__ flag, int n_dst, int n_total) {
    int wid  = (blockIdx.x * blockDim.x + threadIdx.x) >> 6;
    int lane = threadIdx.x & 63;
    if (wid >= n_total) return;
    int isf32 = *flag;
    float tval = 0.0f;
    if (wid >= n_dst) {
        int e = wid - n_dst;
        tval = isf32 ? ((const float*)dt_v)[e] : bf2f(((const unsigned short*)dt_v)[e]);
    }
    int j0 = lane * 2;
    float tf0 = cosf(tval * tw[j0]     + tb[j0]);
    float tf1 = cosf(tval * tw[j0 + 1] + tb[j0 + 1]);
    float h0, h1;
    if (isf32) {
        const float* hp = (const float*)hyper_v + (size_t)wid * 128 + j0;
        h0 = hp[0]; h1 = hp[1];
    } else {
        const unsigned short* hp = (const unsigned short*)hyper_v + (size_t)wid * 128 + j0;
        h0 = bf2f(hp[0]); h1 = bf2f(hp[1]);
    }
    float ptf2 = wred(tf0 * tf0 + tf1 * tf1);
    float ph2  = wred(h0 * h0 + h1 * h1);
    float pht  = wred(h0 * tf0 + h1 * tf1);
    float ntf = sqrtf(fmaxf(ptf2, 1e-30f));
    float maxn = 1.0f - 0.004f;
    float sc = (ntf > maxn) ? (maxn / ntf) : 1.0f;
    float y2 = sc * sc * ptf2, xy = sc * pht, x2 = ph2;
    float A = 1.0f + 2.0f * xy + y2;
    float B = 1.0f - x2;
    float iden = 1.0f / fmaxf(1.0f + 2.0f * xy + x2 * y2, 1e-15f);
    float s0 = (A * h0 + B * sc * tf0) * iden;
    float s1 = (A * h1 + B * sc * tf1) * iden;
    float* sp = sf + (size_t)wid * 128 + j0;
    sp[0] = s0; sp[1] = s1;
    float ps2 = wred(s0 * s0 + s1 * s1);
    float xn = sqrtf(fmaxf(ps2, 1e-30f));
    float g = atanhf(fminf(xn, ACLIP)) / xn;
    if (lane == 0) tnode[wid] = g;
}

// ---------- stage 2: GEMM  C[M,256] = A[M,128] @ W[256,128]^T  (fp32) ----------
__global__ __launch_bounds__(256) void k_gemm(const float* __restrict__ A,
                                              const float* __restrict__ W,
                                              float* __restrict__ C, int M) {
    __shared__ __align__(16) float As[64][32];
    __shared__ __align__(16) float Ws[32][256];
    int t = threadIdx.x;
    int row0 = blockIdx.x * 64;
    int g = t >> 6;
    int c0 = (t & 63) * 4;
    float acc[16][4];
#pragma unroll
    for (int n = 0; n < 16; n++)
#pragma unroll
        for (int j = 0; j < 4; j++) acc[n][j] = 0.0f;

    for (int k0 = 0; k0 < 128; k0 += 32) {
        __syncthreads();
        for (int q = t; q < 512; q += 256) {
            int r = q >> 3, c4 = (q & 7) * 4;
            int rr = min(row0 + r, M - 1);
            float4 v = *(const float4*)(A + (size_t)rr * 128 + k0 + c4);
            *(float4*)&As[r][c4] = v;
        }
        {
            const float* wr = W + (size_t)t * 128 + k0;
#pragma unroll
            for (int kk = 0; kk < 32; kk += 4) {
                float4 v = *(const float4*)(wr + kk);
                Ws[kk + 0][t] = v.x; Ws[kk + 1][t] = v.y;
                Ws[kk + 2][t] = v.z; Ws[kk + 3][t] = v.w;
            }
        }
        __syncthreads();
#pragma unroll
        for (int kk = 0; kk < 32; kk += 4) {
            float4 w0 = *(const float4*)&Ws[kk + 0][c0];
            float4 w1 = *(const float4*)&Ws[kk + 1][c0];
            float4 w2 = *(const float4*)&Ws[kk + 2][c0];
            float4 w3 = *(const float4*)&Ws[kk + 3][c0];
#pragma unroll
            for (int nn = 0; nn < 16; nn++) {
                float4 a4 = *(const float4*)&As[g * 16 + nn][kk];
                acc[nn][0] += a4.x * w0.x + a4.y * w1.x + a4.z * w2.x + a4.w * w3.x;
                acc[nn][1] += a4.x * w0.y + a4.y * w1.y + a4.z * w2.y + a4.w * w3.y;
                acc[nn][2] += a4.x * w0.z + a4.y * w1.z + a4.z * w2.z + a4.w * w3.z;
                acc[nn][3] += a4.x * w0.w + a4.y * w1.w + a4.z * w2.w + a4.w * w3.w;
            }
        }
    }
#pragma unroll
    for (int nn = 0; nn < 16; nn++) {
        int row = row0 + g * 16 + nn;
        if (row < M) {
            float4 v = make_float4(acc[nn][0], acc[nn][1], acc[nn][2], acc[nn][3]);
            *(float4*)(C + (size_t)row * 256 + c0) = v;
        }
    }
}

// ---------- stage 3: per-node epilogue (wave per node, in-place mx -> feat) ----------
__global__ void k_epilogue(float* __restrict__ feat, const float* __restrict__ tnode,
                           const float* __restrict__ bvec, const float* __restrict__ attn,
                           float* __restrict__ x2a, float* __restrict__ ca,
                           float* __restrict__ satt, int base, int cnt) {
    int wid  = (blockIdx.x * blockDim.x + threadIdx.x) >> 6;
    int lane = threadIdx.x & 63;
    if (wid >= cnt) return;
    int node = base + wid;
    float* row = feat + (size_t)node * 256;
    int c = lane * 4;
    float4 mx = *(float4*)(row + c);
    float4 b4 = *(const float4*)(bvec + c);
    float pm2 = wred(mx.x * mx.x + mx.y * mx.y + mx.z * mx.z + mx.w * mx.w);
    float pdb = wred(mx.x * b4.x + mx.y * b4.y + mx.z * b4.z + mx.w * b4.w);
    float pb2 = wred(b4.x * b4.x + b4.y * b4.y + b4.z * b4.z + b4.w * b4.w);
    float g = tnode[node];
    float mxn = sqrtf(fmaxf(pm2, 1e-30f));
    float sv = tanhf(mxn * g) / mxn;
    float xy = sv * pdb;
    float x2v = sv * sv * pm2;
    float y2 = pb2;
    float A = 1.0f + 2.0f * xy + y2;
    float B = 1.0f - x2v;
    float iden = 1.0f / fmaxf(1.0f + 2.0f * xy + x2v * y2, 1e-15f);
    float4 f;
    f.x = (A * sv * mx.x + B * b4.x) * iden;
    f.y = (A * sv * mx.y + B * b4.y) * iden;
    f.z = (A * sv * mx.z + B * b4.z) * iden;
    f.w = (A * sv * mx.w + B * b4.w) * iden;
    *(float4*)(row + c) = f;
    float4 at = *(const float4*)(attn + c);
    float pf2 = f.x * f.x + f.y * f.y + f.z * f.z + f.w * f.w;
    float pfa = f.x * at.x + f.y * at.y + f.z * at.z + f.w * at.w;
    float pa0 = (lane < 32) ? pfa : 0.0f;
    float pa1 = (lane < 32) ? 0.0f : pfa;
    pf2 = wred(pf2); pa0 = wred(pa0); pa1 = wred(pa1);
    float nf = sqrtf(fmaxf(pf2, 1e-30f));
    float cl = atanhf(fminf(nf, ACLIP)) / nf;
    if (lane == 0) {
        x2a[node] = pf2;
        ca[node] = cl;
        satt[(size_t)node * 2 + 0] = cl * pa0;
        satt[(size_t)node * 2 + 1] = cl * pa1;
    }
}

// ---------- stage 4: edge distance, CSR-ordered (wave per slot) ----------
__global__ void k_edge_dist(const float* __restrict__ feat, const float* __restrict__ x2a,
                            const int* __restrict__ es, const int* __restrict__ ed,
                            float* __restrict__ invd, int n_edge) {
    int wid  = (blockIdx.x * blockDim.x + threadIdx.x) >> 6;
    int lane = threadIdx.x & 63;
    if (wid >= n_edge) return;
    int s = es[wid], d = ed[wid];
    int c = lane * 4;
    float4 xv = *(const float4*)(feat + (size_t)s * 256 + c);
    float4 yv = *(const float4*)(feat + (size_t)d * 256 + c);
    float pd = wred(xv.x * yv.x + xv.y * yv.y + xv.z * yv.z + xv.w * yv.w);
    float x2 = x2a[s], y2 = x2a[d];
    float A = 1.0f - 2.0f * pd + y2;
    float B = 1.0f - x2;
    float iden = 1.0f / fmaxf(1.0f - 2.0f * pd + x2 * y2, 1e-15f);
    float n0 = (B * yv.x - A * xv.x) * iden;
    float n1 = (B * yv.y - A * xv.y) * iden;
    float n2 = (B * yv.z - A * xv.z) * iden;
    float n3 = (B * yv.w - A * xv.w) * iden;
    float p2 = wred(n0 * n0 + n1 * n1 + n2 * n2 + n3 * n3);
    if (lane == 0) {
        float nrm = sqrtf(fmaxf(p2, 1e-30f));
        float dd = 2.0f * atanhf(fminf(nrm, ACLIP));
        invd[wid] = 1.0f / (1e-15f + dd);
    }
}

// ---------- stage 5: per-dst segment softmaxes + gather + expmap0 (block per dst) ----------
__global__ __launch_bounds__(256) void k_aggregate(
        const int* __restrict__ rowptr, const int* __restrict__ es,
        const float* __restrict__ invd, const float* __restrict__ satt,
        const float* __restrict__ ca, const float* __restrict__ feat,
        void* __restrict__ out, const int* __restrict__ flag, int n_dst) {
    __shared__ float red[4];
    __shared__ float w0b[256], w1b[256];
    __shared__ int sb[256];
    int d = blockIdx.x;
    int t = threadIdx.x;
    int off0 = rowptr[d], off1 = rowptr[d + 1];
    int col = t, h = col >> 7;
    if (off0 == off1) {   // empty segment -> expmap0(0) = 0
        if (*flag) ((float*)out)[(size_t)d * 256 + col] = 0.0f;
        else ((unsigned short*)out)[(size_t)d * 256 + col] = 0;
        return;
    }
    // softmax 1 (dist-based): max, then sum
    float m1 = -INFINITY;
    for (int i = off0 + t; i < off1; i += 256) m1 = fmaxf(m1, invd[i]);
    m1 = bmax(m1, red);
    float s1 = 0.0f;
    for (int i = off0 + t; i < off1; i += 256) s1 += expf(invd[i] - m1);
    s1 = bsum(s1, red);
    float is1 = 1.0f / s1;
    float sd0 = satt[(size_t)d * 2 + 0], sd1 = satt[(size_t)d * 2 + 1];
    // softmax 2 (attention logits after leaky-relu): max, then sum
    float m20 = -INFINITY, m21 = -INFINITY;
    for (int i = off0 + t; i < off1; i += 256) {
        int s = es[i];
        float dsm = expf(invd[i] - m1) * is1;
        float e0 = (satt[(size_t)s * 2 + 0] + sd0) * dsm; e0 = (e0 > 0.0f) ? e0 : 0.2f * e0;
        float e1 = (satt[(size_t)s * 2 + 1] + sd1) * dsm; e1 = (e1 > 0.0f) ? e1 : 0.2f * e1;
        m20 = fmaxf(m20, e0); m21 = fmaxf(m21, e1);
    }
    m20 = bmax(m20, red); m21 = bmax(m21, red);
    float s20 = 0.0f, s21 = 0.0f;
    for (int i = off0 + t; i < off1; i += 256) {
        int s = es[i];
        float dsm = expf(invd[i] - m1) * is1;
        float e0 = (satt[(size_t)s * 2 + 0] + sd0) * dsm; e0 = (e0 > 0.0f) ? e0 : 0.2f * e0;
        float e1 = (satt[(size_t)s * 2 + 1] + sd1) * dsm; e1 = (e1 > 0.0f) ? e1 : 0.2f * e1;
        s20 += expf(e0 - m20); s21 += expf(e1 - m21);
    }
    s20 = bsum(s20, red); s21 = bsum(s21, red);
    float is20 = 1.0f / s20, is21 = 1.0f / s21;
    // gather: acc[col] = sum_e a_e * ca[s_e] * feat[s_e][col]
    float acc = 0.0f;
    for (int base = off0; base < off1; base += 256) {
        int i = base + t;
        if (i < off1) {
            int s = es[i];
            float dsm = expf(invd[i] - m1) * is1;
            float e0 = (satt[(size_t)s * 2 + 0] + sd0) * dsm; e0 = (e0 > 0.0f) ? e0 : 0.2f * e0;
            float e1 = (satt[(size_t)s * 2 + 1] + sd1) * dsm; e1 = (e1 > 0.0f) ? e1 : 0.2f * e1;
            float cs = ca[s];
            w0b[t] = expf(e0 - m20) * is20 * cs;
            w1b[t] = expf(e1 - m21) * is21 * cs;
            sb[t] = s;
        }
        __syncthreads();
        int cnt = min(256, off1 - base);
        for (int j = 0; j < cnt; j++) {
            float w = h ? w1b[j] : w0b[j];
            acc += w * feat[(size_t)sb[j] * 256 + col];
        }
        __syncthreads();
    }
    // expmap0
    float p2 = bsum(acc * acc, red);
    float n = sqrtf(fmaxf(p2, 1e-30f));
    float sc = tanhf(n) / n;
    float o = acc * sc;
    if (*flag) ((float*)out)[(size_t)d * 256 + col] = o;
    else ((unsigned short*)out)[(size_t)d * 256 + col] = f2bf(o);
}

// ---------- host ----------
extern "C" void kernel_launch(void* const* d_in, const int* in_sizes, int n_in,
                              void* d_out, int out_size, void* d_ws, size_t ws_size,
                              hipStream_t stream) {
    const void* hyper  = d_in[0];
    const void* dt     = d_in[1];
    const void* time_w = d_in[2];
    const void* time_b = d_in[3];
    const void* w_src  = d_in[4];
    const void* b_src  = d_in[5];
    const void* w_dst  = d_in[6];
    const void* b_dst  = d_in[7];
    const void* attn   = d_in[8];
    const int* src_idx = (const int*)d_in[9];
    const int* dst_idx = (const int*)d_in[10];

    const int DIMN = 128, HD = 256;
    int n_edge  = in_sizes[1];
    int n_total = in_sizes[0] / DIMN;
    int n_dst   = n_total - n_edge;

    float* ws = (float*)d_ws;
    size_t off = 0;
    auto alloc = [&](size_t n) { float* p = ws + off; off += n; return p; };
    float* p_tw    = alloc(DIMN);
    float* p_tb    = alloc(DIMN);
    float* p_wsrc  = alloc((size_t)HD * DIMN);
    float* p_wdst  = alloc((size_t)HD * DIMN);
    float* p_bsrc  = alloc(HD);
    float* p_bdst  = alloc(HD);
    float* p_attn  = alloc(HD);
    int*   p_flag  = (int*)alloc(4);
    // CSR
    int* p_deg    = (int*)alloc(n_dst);
    int* p_rowptr = (int*)alloc(n_dst + 1);
    int* p_cursor = (int*)alloc(n_dst);
    int* p_es     = (int*)alloc(n_edge);
    int* p_ed     = (int*)alloc(n_edge);
    float* p_inv  = alloc(n_edge);
    // big buffers
    float* p_sf    = alloc((size_t)n_total * DIMN);
    float* p_mx    = alloc((size_t)n_total * HD);     // mx, then feat in-place
    float* p_tnode = alloc(n_total);
    float* p_call  = alloc(n_total);
    float* p_x2    = alloc(n_total);
    float* p_satt  = alloc((size_t)n_total * 2);
    (void)ws_size;

    const int TB = 256;
    auto cdiv = [](int a, int b) { return (a + b - 1) / b; };

    // dtype detection
    k_detect<<<1, TB, 0, stream>>>((const unsigned short*)hyper, p_flag);

    // param conversion -> fp32
    k_cvt<<<cdiv(DIMN, TB), TB, 0, stream>>>(time_w, p_tw, DIMN, p_flag);
    k_cvt<<<cdiv(DIMN, TB), TB, 0, stream>>>(time_b, p_tb, DIMN, p_flag);
    k_cvt<<<cdiv(HD * DIMN, TB), TB, 0, stream>>>(w_src, p_wsrc, HD * DIMN, p_flag);
    k_cvt<<<cdiv(HD * DIMN, TB), TB, 0, stream>>>(w_dst, p_wdst, HD * DIMN, p_flag);
    k_cvt<<<cdiv(HD, TB), TB, 0, stream>>>(b_src, p_bsrc, HD, p_flag);
    k_cvt<<<cdiv(HD, TB), TB, 0, stream>>>(b_dst, p_bdst, HD, p_flag);
    k_cvt<<<cdiv(HD, TB), TB, 0, stream>>>(attn, p_attn, HD, p_flag);

    // CSR build
    k_fill<<<cdiv(n_dst, TB), TB, 0, stream>>>((unsigned*)p_deg, 0u, n_dst);
    k_hist<<<cdiv(n_edge, TB), TB, 0, stream>>>(dst_idx, p_deg, n_edge);
    k_scan<<<1, 1024, 0, stream>>>(p_deg, p_rowptr, p_cursor, n_dst);
    k_scatter_edges<<<cdiv(n_edge, TB), TB, 0, stream>>>(src_idx, dst_idx, p_cursor,
                                                         p_es, p_ed, n_edge);

    // stage 1: node prologue
    k_node_prep<<<cdiv(n_total, 4), TB, 0, stream>>>(hyper, dt, p_tw, p_tb,
                                                     p_sf, p_tnode, p_flag, n_dst, n_total);

    // stage 2: GEMMs
    k_gemm<<<cdiv(n_dst, 64), TB, 0, stream>>>(p_sf, p_wdst, p_mx, n_dst);
    k_gemm<<<cdiv(n_edge, 64), TB, 0, stream>>>(p_sf + (size_t)n_dst * DIMN, p_wsrc,
                                                p_mx + (size_t)n_dst * HD, n_edge);

    // stage 3: epilogues (mx -> feat in place, + per-node scalars)
    k_epilogue<<<cdiv(n_dst, 4), TB, 0, stream>>>(p_mx, p_tnode, p_bdst, p_attn,
                                                  p_x2, p_call, p_satt, 0, n_dst);
    k_epilogue<<<cdiv(n_edge, 4), TB, 0, stream>>>(p_mx, p_tnode, p_bsrc, p_attn,
                                                   p_x2, p_call, p_satt, n_dst, n_edge);

    // stage 4: edge distances (CSR order)
    k_edge_dist<<<cdiv(n_edge, 4), TB, 0, stream>>>(p_mx, p_x2, p_es, p_ed, p_inv, n_edge);

    // stage 5: segment softmaxes + gather + expmap0 -> out
    k_aggregate<<<n_dst, TB, 0, stream>>>(p_rowptr, p_es, p_inv, p_satt, p_call,
                                          p_mx, d_out, p_flag, n_dst);
}

// Round 4
// 791.347 us; speedup vs baseline: 2.2077x; 1.4056x over previous
//
#include <hip/hip_runtime.h>
#include <hip/hip_bf16.h>
#include <math.h>

typedef __attribute__((ext_vector_type(8))) short bfrag8;
typedef __attribute__((ext_vector_type(4))) float ffrag4;

// ---------- helpers ----------
__device__ inline float bf2f(unsigned short h) { return __uint_as_float(((unsigned)h) << 16); }
__device__ inline unsigned short f2bf(float f) {
    unsigned u = __float_as_uint(f);
    unsigned r = (u + 0x7FFFu + ((u >> 16) & 1u)) >> 16;
    return (unsigned short)r;
}
__device__ inline float wred(float v) {
    v += __shfl_xor(v, 1, 64);
    v += __shfl_xor(v, 2, 64);
    v += __shfl_xor(v, 4, 64);
    v += __shfl_xor(v, 8, 64);
    v += __shfl_xor(v, 16, 64);
    v += __shfl_xor(v, 32, 64);
    return v;
}
__device__ inline float wredmax(float v) {
    v = fmaxf(v, __shfl_xor(v, 1, 64));
    v = fmaxf(v, __shfl_xor(v, 2, 64));
    v = fmaxf(v, __shfl_xor(v, 4, 64));
    v = fmaxf(v, __shfl_xor(v, 8, 64));
    v = fmaxf(v, __shfl_xor(v, 16, 64));
    v = fmaxf(v, __shfl_xor(v, 32, 64));
    return v;
}
__device__ inline float bsum(float v, float* red) {
    v = wred(v);
    if ((threadIdx.x & 63) == 0) red[threadIdx.x >> 6] = v;
    __syncthreads();
    float r = red[0] + red[1] + red[2] + red[3];
    __syncthreads();
    return r;
}
__device__ inline float bmax(float v, float* red) {
    v = wredmax(v);
    if ((threadIdx.x & 63) == 0) red[threadIdx.x >> 6] = v;
    __syncthreads();
    float r = fmaxf(fmaxf(red[0], red[1]), fmaxf(red[2], red[3]));
    __syncthreads();
    return r;
}

#define ACLIP (1.0f - 1e-7f)

// ---------- dtype detection ----------
__global__ void k_detect(const unsigned short* __restrict__ hyper, int* __restrict__ flag) {
    __shared__ int total;
    int t = threadIdx.x;
    if (t == 0) total = 0;
    __syncthreads();
    int cnt = 0;
    for (int i = t * 8; i < t * 8 + 8; i++) {
        if ((i & 1) == 0) {
            unsigned e = ((unsigned)hyper[i] >> 7) & 0xFF;
            if (e >= 0xC0) cnt++;
        }
    }
    atomicAdd(&total, cnt);
    __syncthreads();
    if (t == 0) *flag = (total >= 32) ? 1 : 0;   // 1 = inputs are float32
}

// ---------- converters / fills ----------
__global__ void k_cvt(const void* __restrict__ s, float* __restrict__ d, int n,
                      const int* __restrict__ flag) {
    int i = blockIdx.x * blockDim.x + threadIdx.x;
    if (i >= n) return;
    if (*flag) d[i] = ((const float*)s)[i];
    else       d[i] = bf2f(((const unsigned short*)s)[i]);
}
// split input into bf16 hi/lo pair (hi = rne(x), lo = rne(x - hi))
__global__ void k_wsplit(const void* __restrict__ s, unsigned short* __restrict__ hi,
                         unsigned short* __restrict__ lo, int n, const int* __restrict__ flag) {
    int i = blockIdx.x * blockDim.x + threadIdx.x;
    if (i >= n) return;
    float x = (*flag) ? ((const float*)s)[i] : bf2f(((const unsigned short*)s)[i]);
    unsigned short h = f2bf(x);
    hi[i] = h;
    lo[i] = f2bf(x - bf2f(h));
}
__global__ void k_fill(unsigned* __restrict__ p, unsigned v, int n) {
    int i = blockIdx.x * blockDim.x + threadIdx.x;
    if (i < n) p[i] = v;
}

// ---------- CSR build ----------
__global__ void k_hist(const int* __restrict__ dst_idx, int* __restrict__ deg, int n_edge) {
    int i = blockIdx.x * blockDim.x + threadIdx.x;
    if (i < n_edge) atomicAdd(deg + dst_idx[i], 1);
}
__global__ __launch_bounds__(1024) void k_scan(const int* __restrict__ deg,
                                               int* __restrict__ rowptr,
                                               int* __restrict__ cursor, int n) {
    __shared__ int part[1024];
    int t = threadIdx.x;
    int chunk = (n + 1023) >> 10;
    int lo = t * chunk, hi = min(lo + chunk, n);
    int s = 0;
    for (int i = lo; i < hi; i++) s += deg[i];
    part[t] = s;
    __syncthreads();
    for (int dd = 1; dd < 1024; dd <<= 1) {
        int v = (t >= dd) ? part[t - dd] : 0;
        __syncthreads();
        part[t] += v;
        __syncthreads();
    }
    int base = (t == 0) ? 0 : part[t - 1];
    for (int i = lo; i < hi; i++) {
        rowptr[i] = base; cursor[i] = base;
        base += deg[i];
    }
    if (t == 0) rowptr[n] = part[1023];
}
__global__ void k_scatter_edges(const int* __restrict__ src_idx, const int* __restrict__ dst_idx,
                                int* __restrict__ cursor, int* __restrict__ es,
                                int* __restrict__ ed, int n_edge) {
    int i = blockIdx.x * blockDim.x + threadIdx.x;
    if (i >= n_edge) return;
    int d = dst_idx[i];
    int slot = atomicAdd(cursor + d, 1);
    es[slot] = src_idx[i];
    ed[slot] = d;
}

// ---------- stage 1: per-node prologue (wave per node) -> Ah/Al bf16 split ----------
__global__ void k_node_prep(const void* __restrict__ hyper_v,
                            const void* __restrict__ dt_v,
                            const float* __restrict__ tw, const float* __restrict__ tb,
                            unsigned short* __restrict__ Ah, unsigned short* __restrict__ Al,
                            float* __restrict__ tnode,
                            const int* __restrict__ flag, int n_dst, int n_total) {
    int wid  = (blockIdx.x * blockDim.x + threadIdx.x) >> 6;
    int lane = threadIdx.x & 63;
    if (wid >= n_total) return;
    int isf32 = *flag;
    float tval = 0.0f;
    if (wid >= n_dst) {
        int e = wid - n_dst;
        tval = isf32 ? ((const float*)dt_v)[e] : bf2f(((const unsigned short*)dt_v)[e]);
    }
    int j0 = lane * 2;
    float tf0 = cosf(tval * tw[j0]     + tb[j0]);
    float tf1 = cosf(tval * tw[j0 + 1] + tb[j0 + 1]);
    float h0, h1;
    if (isf32) {
        const float* hp = (const float*)hyper_v + (size_t)wid * 128 + j0;
        h0 = hp[0]; h1 = hp[1];
    } else {
        const unsigned short* hp = (const unsigned short*)hyper_v + (size_t)wid * 128 + j0;
        h0 = bf2f(hp[0]); h1 = bf2f(hp[1]);
    }
    float ptf2 = wred(tf0 * tf0 + tf1 * tf1);
    float ph2  = wred(h0 * h0 + h1 * h1);
    float pht  = wred(h0 * tf0 + h1 * tf1);
    float ntf = sqrtf(fmaxf(ptf2, 1e-30f));
    float maxn = 1.0f - 0.004f;
    float sc = (ntf > maxn) ? (maxn / ntf) : 1.0f;
    float y2 = sc * sc * ptf2, xy = sc * pht, x2 = ph2;
    float A = 1.0f + 2.0f * xy + y2;
    float B = 1.0f - x2;
    float iden = 1.0f / fmaxf(1.0f + 2.0f * xy + x2 * y2, 1e-15f);
    float s0 = (A * h0 + B * sc * tf0) * iden;
    float s1 = (A * h1 + B * sc * tf1) * iden;
    unsigned short h0s = f2bf(s0), h1s = f2bf(s1);
    unsigned short l0s = f2bf(s0 - bf2f(h0s)), l1s = f2bf(s1 - bf2f(h1s));
    *(ushort2*)(Ah + (size_t)wid * 128 + j0) = make_ushort2(h0s, h1s);
    *(ushort2*)(Al + (size_t)wid * 128 + j0) = make_ushort2(l0s, l1s);
    float ps2 = wred(s0 * s0 + s1 * s1);
    float xn = sqrtf(fmaxf(ps2, 1e-30f));
    float g = atanhf(fminf(xn, ACLIP)) / xn;
    if (lane == 0) tnode[wid] = g;
}

// ---------- stage 2+3 fused: split-bf16 MFMA GEMM + mobius/logmap epilogue ----------
// C[M,256] = A[M,128] @ W[256,128]^T via 16x16x32 bf16 MFMA, A=Ah+Al, W=Wh+Wl.
// Epilogue entirely in MFMA C-layout (col=lane&15, row=(lane>>4)*4+reg).
__global__ __launch_bounds__(256) void k_gemm_ep(
        const unsigned short* __restrict__ Ah, const unsigned short* __restrict__ Al,
        const unsigned short* __restrict__ Wh, const unsigned short* __restrict__ Wl,
        const float* __restrict__ bvec, const float* __restrict__ attn,
        const float* __restrict__ tnode,
        float* __restrict__ feat, float* __restrict__ x2a, float* __restrict__ ca,
        float* __restrict__ satt, int base, int M) {
    int w = threadIdx.x >> 6, lane = threadIdx.x & 63;
    int m16 = lane & 15, kg = lane >> 4;     // kg = k-group / row-group quad
    int strip = blockIdx.x * 4 + w;          // 16-row strip
    int arow = min(strip * 16 + m16, M - 1); // A-operand row (m = lane&15)
    ffrag4 acc[16];
#pragma unroll
    for (int ct = 0; ct < 16; ct++) acc[ct] = (ffrag4){0.0f, 0.0f, 0.0f, 0.0f};

    const size_t abase = (size_t)arow * 128 + kg * 8;
    for (int ks = 0; ks < 4; ks++) {
        int k0 = ks * 32;
        bfrag8 ah = *(const bfrag8*)(Ah + abase + k0);
        bfrag8 al = *(const bfrag8*)(Al + abase + k0);
#pragma unroll
        for (int ct = 0; ct < 16; ct++) {
            size_t wb = (size_t)(ct * 16 + m16) * 128 + kg * 8 + k0;
            bfrag8 bh = *(const bfrag8*)(Wh + wb);
            bfrag8 bl = *(const bfrag8*)(Wl + wb);
            acc[ct] = __builtin_amdgcn_mfma_f32_16x16x32_bf16(ah, bh, acc[ct], 0, 0, 0);
            acc[ct] = __builtin_amdgcn_mfma_f32_16x16x32_bf16(al, bh, acc[ct], 0, 0, 0);
            acc[ct] = __builtin_amdgcn_mfma_f32_16x16x32_bf16(ah, bl, acc[ct], 0, 0, 0);
        }
    }

    // ---- epilogue in C-layout: lane holds rows kg*4+r (r=0..3), col ct*16+m16 ----
    float bv[16], av[16];
#pragma unroll
    for (int ct = 0; ct < 16; ct++) {
        bv[ct] = bvec[ct * 16 + m16];
        av[ct] = attn[ct * 16 + m16];
    }
    float pm2[4] = {0, 0, 0, 0}, pdb[4] = {0, 0, 0, 0};
    float pb2 = 0.0f;
#pragma unroll
    for (int ct = 0; ct < 16; ct++) {
        pb2 += bv[ct] * bv[ct];
#pragma unroll
        for (int r = 0; r < 4; r++) {
            float v = acc[ct][r];
            pm2[r] += v * v;
            pdb[r] += v * bv[ct];
        }
    }
#pragma unroll
    for (int off = 1; off < 16; off <<= 1) {
        pb2 += __shfl_xor(pb2, off, 64);
#pragma unroll
        for (int r = 0; r < 4; r++) {
            pm2[r] += __shfl_xor(pm2[r], off, 64);
            pdb[r] += __shfl_xor(pdb[r], off, 64);
        }
    }
#pragma unroll
    for (int r = 0; r < 4; r++) {
        int row_o = strip * 16 + kg * 4 + r;
        bool ok = row_o < M;
        float g = ok ? tnode[base + row_o] : 1.0f;
        float mxn = sqrtf(fmaxf(pm2[r], 1e-30f));
        float sv = tanhf(mxn * g) / mxn;
        float xy = sv * pdb[r];
        float x2v = sv * sv * pm2[r];
        float Am = 1.0f + 2.0f * xy + pb2;
        float Bm = 1.0f - x2v;
        float iden = 1.0f / fmaxf(1.0f + 2.0f * xy + x2v * pb2, 1e-15f);
        float pf2 = 0.0f, pa0 = 0.0f, pa1 = 0.0f;
#pragma unroll
        for (int ct = 0; ct < 16; ct++) {
            float f = (Am * sv * acc[ct][r] + Bm * bv[ct]) * iden;
            acc[ct][r] = f;
            pf2 += f * f;
            if (ct < 8) pa0 += f * av[ct]; else pa1 += f * av[ct];
        }
#pragma unroll
        for (int off = 1; off < 16; off <<= 1) {
            pf2 += __shfl_xor(pf2, off, 64);
            pa0 += __shfl_xor(pa0, off, 64);
            pa1 += __shfl_xor(pa1, off, 64);
        }
        if (ok) {
            float* fr = feat + (size_t)(base + row_o) * 256;
#pragma unroll
            for (int ct = 0; ct < 16; ct++) fr[ct * 16 + m16] = acc[ct][r];
            if (m16 == 0) {
                float nf = sqrtf(fmaxf(pf2, 1e-30f));
                float cl = atanhf(fminf(nf, ACLIP)) / nf;
                x2a[base + row_o] = pf2;
                ca[base + row_o] = cl;
                satt[(size_t)(base + row_o) * 2 + 0] = cl * pa0;
                satt[(size_t)(base + row_o) * 2 + 1] = cl * pa1;
            }
        }
    }
}

// ---------- stage 4: edge distance, CSR-ordered (wave per slot) ----------
__global__ void k_edge_dist(const float* __restrict__ feat, const float* __restrict__ x2a,
                            const int* __restrict__ es, const int* __restrict__ ed,
                            float* __restrict__ invd, int n_edge) {
    int wid  = (blockIdx.x * blockDim.x + threadIdx.x) >> 6;
    int lane = threadIdx.x & 63;
    if (wid >= n_edge) return;
    int s = es[wid], d = ed[wid];
    int c = lane * 4;
    float4 xv = *(const float4*)(feat + (size_t)s * 256 + c);
    float4 yv = *(const float4*)(feat + (size_t)d * 256 + c);
    float pd = wred(xv.x * yv.x + xv.y * yv.y + xv.z * yv.z + xv.w * yv.w);
    float x2 = x2a[s], y2 = x2a[d];
    float A = 1.0f - 2.0f * pd + y2;
    float B = 1.0f - x2;
    float iden = 1.0f / fmaxf(1.0f - 2.0f * pd + x2 * y2, 1e-15f);
    float n0 = (B * yv.x - A * xv.x) * iden;
    float n1 = (B * yv.y - A * xv.y) * iden;
    float n2 = (B * yv.z - A * xv.z) * iden;
    float n3 = (B * yv.w - A * xv.w) * iden;
    float p2 = wred(n0 * n0 + n1 * n1 + n2 * n2 + n3 * n3);
    if (lane == 0) {
        float nrm = sqrtf(fmaxf(p2, 1e-30f));
        float dd = 2.0f * atanhf(fminf(nrm, ACLIP));
        invd[wid] = 1.0f / (1e-15f + dd);
    }
}

// ---------- stage 5: per-dst segment softmaxes + gather + expmap0 (block per dst) ----------
__global__ __launch_bounds__(256) void k_aggregate(
        const int* __restrict__ rowptr, const int* __restrict__ es,
        const float* __restrict__ invd, const float* __restrict__ satt,
        const float* __restrict__ ca, const float* __restrict__ feat,
        void* __restrict__ out, const int* __restrict__ flag, int n_dst) {
    __shared__ float red[4];
    __shared__ float w0b[256], w1b[256];
    __shared__ int sb[256];
    int d = blockIdx.x;
    int t = threadIdx.x;
    int off0 = rowptr[d], off1 = rowptr[d + 1];
    int col = t, h = col >> 7;
    if (off0 == off1) {
        if (*flag) ((float*)out)[(size_t)d * 256 + col] = 0.0f;
        else ((unsigned short*)out)[(size_t)d * 256 + col] = 0;
        return;
    }
    float m1 = -INFINITY;
    for (int i = off0 + t; i < off1; i += 256) m1 = fmaxf(m1, invd[i]);
    m1 = bmax(m1, red);
    float s1 = 0.0f;
    for (int i = off0 + t; i < off1; i += 256) s1 += expf(invd[i] - m1);
    s1 = bsum(s1, red);
    float is1 = 1.0f / s1;
    float sd0 = satt[(size_t)d * 2 + 0], sd1 = satt[(size_t)d * 2 + 1];
    float m20 = -INFINITY, m21 = -INFINITY;
    for (int i = off0 + t; i < off1; i += 256) {
        int s = es[i];
        float dsm = expf(invd[i] - m1) * is1;
        float e0 = (satt[(size_t)s * 2 + 0] + sd0) * dsm; e0 = (e0 > 0.0f) ? e0 : 0.2f * e0;
        float e1 = (satt[(size_t)s * 2 + 1] + sd1) * dsm; e1 = (e1 > 0.0f) ? e1 : 0.2f * e1;
        m20 = fmaxf(m20, e0); m21 = fmaxf(m21, e1);
    }
    m20 = bmax(m20, red); m21 = bmax(m21, red);
    float s20 = 0.0f, s21 = 0.0f;
    for (int i = off0 + t; i < off1; i += 256) {
        int s = es[i];
        float dsm = expf(invd[i] - m1) * is1;
        float e0 = (satt[(size_t)s * 2 + 0] + sd0) * dsm; e0 = (e0 > 0.0f) ? e0 : 0.2f * e0;
        float e1 = (satt[(size_t)s * 2 + 1] + sd1) * dsm; e1 = (e1 > 0.0f) ? e1 : 0.2f * e1;
        s20 += expf(e0 - m20); s21 += expf(e1 - m21);
    }
    s20 = bsum(s20, red); s21 = bsum(s21, red);
    float is20 = 1.0f / s20, is21 = 1.0f / s21;
    float acc = 0.0f;
    for (int bbase = off0; bbase < off1; bbase += 256) {
        int i = bbase + t;
        if (i < off1) {
            int s = es[i];
            float dsm = expf(invd[i] - m1) * is1;
            float e0 = (satt[(size_t)s * 2 + 0] + sd0) * dsm; e0 = (e0 > 0.0f) ? e0 : 0.2f * e0;
            float e1 = (satt[(size_t)s * 2 + 1] + sd1) * dsm; e1 = (e1 > 0.0f) ? e1 : 0.2f * e1;
            float cs = ca[s];
            w0b[t] = expf(e0 - m20) * is20 * cs;
            w1b[t] = expf(e1 - m21) * is21 * cs;
            sb[t] = s;
        }
        __syncthreads();
        int cnt = min(256, off1 - bbase);
        for (int j = 0; j < cnt; j++) {
            float w = h ? w1b[j] : w0b[j];
            acc += w * feat[(size_t)sb[j] * 256 + col];
        }
        __syncthreads();
    }
    float p2 = bsum(acc * acc, red);
    float n = sqrtf(fmaxf(p2, 1e-30f));
    float sc = tanhf(n) / n;
    float o = acc * sc;
    if (*flag) ((float*)out)[(size_t)d * 256 + col] = o;
    else ((unsigned short*)out)[(size_t)d * 256 + col] = f2bf(o);
}

// ---------- host ----------
extern "C" void kernel_launch(void* const* d_in, const int* in_sizes, int n_in,
                              void* d_out, int out_size, void* d_ws, size_t ws_size,
                              hipStream_t stream) {
    const void* hyper  = d_in[0];
    const void* dt     = d_in[1];
    const void* time_w = d_in[2];
    const void* time_b = d_in[3];
    const void* w_src  = d_in[4];
    const void* b_src  = d_in[5];
    const void* w_dst  = d_in[6];
    const void* b_dst  = d_in[7];
    const void* attn   = d_in[8];
    const int* src_idx = (const int*)d_in[9];
    const int* dst_idx = (const int*)d_in[10];

    const int DIMN = 128, HD = 256;
    int n_edge  = in_sizes[1];
    int n_total = in_sizes[0] / DIMN;
    int n_dst   = n_total - n_edge;

    float* ws = (float*)d_ws;
    size_t off = 0;
    auto alloc = [&](size_t n) { float* p = ws + off; off += n; return p; };
    float* p_tw    = alloc(DIMN);
    float* p_tb    = alloc(DIMN);
    float* p_bsrc  = alloc(HD);
    float* p_bdst  = alloc(HD);
    float* p_attn  = alloc(HD);
    int*   p_flag  = (int*)alloc(4);
    // W splits (bf16 hi/lo), 256x128 ushorts each = 16384 floats
    unsigned short* p_whs = (unsigned short*)alloc((size_t)HD * DIMN / 2);
    unsigned short* p_wls = (unsigned short*)alloc((size_t)HD * DIMN / 2);
    unsigned short* p_whd = (unsigned short*)alloc((size_t)HD * DIMN / 2);
    unsigned short* p_wld = (unsigned short*)alloc((size_t)HD * DIMN / 2);
    // A splits (bf16 hi/lo), n_total x 128 ushorts each
    unsigned short* p_ah = (unsigned short*)alloc((size_t)n_total * DIMN / 2);
    unsigned short* p_al = (unsigned short*)alloc((size_t)n_total * DIMN / 2);
    // CSR
    int* p_deg    = (int*)alloc(n_dst);
    int* p_rowptr = (int*)alloc(n_dst + 1);
    int* p_cursor = (int*)alloc(n_dst);
    int* p_es     = (int*)alloc(n_edge);
    int* p_ed     = (int*)alloc(n_edge);
    float* p_inv  = alloc(n_edge);
    // big buffers
    float* p_feat  = alloc((size_t)n_total * HD);
    float* p_tnode = alloc(n_total);
    float* p_call  = alloc(n_total);
    float* p_x2    = alloc(n_total);
    float* p_satt  = alloc((size_t)n_total * 2);
    (void)ws_size;

    const int TB = 256;
    auto cdiv = [](int a, int b) { return (a + b - 1) / b; };

    // dtype detection
    k_detect<<<1, TB, 0, stream>>>((const unsigned short*)hyper, p_flag);

    // small param conversion -> fp32 / bf16-splits
    k_cvt<<<1, TB, 0, stream>>>(time_w, p_tw, DIMN, p_flag);
    k_cvt<<<1, TB, 0, stream>>>(time_b, p_tb, DIMN, p_flag);
    k_cvt<<<1, TB, 0, stream>>>(b_src, p_bsrc, HD, p_flag);
    k_cvt<<<1, TB, 0, stream>>>(b_dst, p_bdst, HD, p_flag);
    k_cvt<<<1, TB, 0, stream>>>(attn, p_attn, HD, p_flag);
    k_wsplit<<<cdiv(HD * DIMN, TB), TB, 0, stream>>>(w_src, p_whs, p_wls, HD * DIMN, p_flag);
    k_wsplit<<<cdiv(HD * DIMN, TB), TB, 0, stream>>>(w_dst, p_whd, p_wld, HD * DIMN, p_flag);

    // CSR build
    k_fill<<<cdiv(n_dst, TB), TB, 0, stream>>>((unsigned*)p_deg, 0u, n_dst);
    k_hist<<<cdiv(n_edge, TB), TB, 0, stream>>>(dst_idx, p_deg, n_edge);
    k_scan<<<1, 1024, 0, stream>>>(p_deg, p_rowptr, p_cursor, n_dst);
    k_scatter_edges<<<cdiv(n_edge, TB), TB, 0, stream>>>(src_idx, dst_idx, p_cursor,
                                                         p_es, p_ed, n_edge);

    // stage 1: node prologue -> Ah/Al + tnode
    k_node_prep<<<cdiv(n_total, 4), TB, 0, stream>>>(hyper, dt, p_tw, p_tb,
                                                     p_ah, p_al, p_tnode, p_flag,
                                                     n_dst, n_total);

    // stage 2+3: fused MFMA GEMM + epilogue (dst then src)
    k_gemm_ep<<<cdiv(n_dst, 64), TB, 0, stream>>>(p_ah, p_al, p_whd, p_wld,
                                                  p_bdst, p_attn, p_tnode,
                                                  p_feat, p_x2, p_call, p_satt, 0, n_dst);
    k_gemm_ep<<<cdiv(n_edge, 64), TB, 0, stream>>>(p_ah + (size_t)n_dst * DIMN,
                                                   p_al + (size_t)n_dst * DIMN,
                                                   p_whs, p_wls,
                                                   p_bsrc, p_attn, p_tnode,
                                                   p_feat, p_x2, p_call, p_satt,
                                                   n_dst, n_edge);

    // stage 4: edge distances (CSR order)
    k_edge_dist<<<cdiv(n_edge, 4), TB, 0, stream>>>(p_feat, p_x2, p_es, p_ed, p_inv, n_edge);

    // stage 5: segment softmaxes + gather + expmap0 -> out
    k_aggregate<<<n_dst, TB, 0, stream>>>(p_rowptr, p_es, p_inv, p_satt, p_call,
                                          p_feat, d_out, p_flag, n_dst);
}